// Round 23
// baseline (488.260 us; speedup 1.0000x reference)
//
#include <hip/hip_runtime.h>
#include <math.h>

#define N_NODES 50000
#define N_EDGES 800000
#define FDIM 128
#define KCLS 10

typedef float v2f __attribute__((ext_vector_type(2)));
typedef short bf16x8 __attribute__((ext_vector_type(8)));
typedef float f32x4 __attribute__((ext_vector_type(4)));

__device__ __forceinline__ v2f pksplat(float a) { v2f r; r.x = a; r.y = a; return r; }
__device__ __forceinline__ v2f pkfma(v2f a, v2f b, v2f c) { return __builtin_elementwise_fma(a, b, c); }
__device__ __forceinline__ v2f pklrelu(v2f v) {
    v2f z = pksplat(0.f);
    v2f mx = __builtin_elementwise_max(v, z);
    v2f mn = __builtin_elementwise_min(v, z);
    return pkfma(pksplat(0.2f), mn, mx);
}
__device__ __forceinline__ int rfl(int v) { return __builtin_amdgcn_readfirstlane(v); }

// fp32 -> bf16 bits, round-to-nearest-even
__device__ __forceinline__ unsigned int f2bfu(float f) {
    unsigned int u = __float_as_uint(f);
    u += 0x7FFFu + ((u >> 16) & 1u);
    return u >> 16;
}

// sum over each 32-lane half, all lanes receive the result.
__device__ __forceinline__ float half_sum32(float x) {
    int v;
    v = __builtin_amdgcn_update_dpp(0, __float_as_int(x), 0xB1, 0xF, 0xF, true);   // quad_perm(1,0,3,2)
    x += __int_as_float(v);
    v = __builtin_amdgcn_update_dpp(0, __float_as_int(x), 0x4E, 0xF, 0xF, true);   // quad_perm(2,3,0,1)
    x += __int_as_float(v);
    v = __builtin_amdgcn_update_dpp(0, __float_as_int(x), 0x124, 0xF, 0xF, true);  // row_ror:4
    x += __int_as_float(v);
    v = __builtin_amdgcn_update_dpp(0, __float_as_int(x), 0x128, 0xF, 0xF, true);  // row_ror:8
    x += __int_as_float(v);
    v = __builtin_amdgcn_ds_swizzle(__float_as_int(x), 0x401F);                    // xor16
    x += __int_as_float(v);
    return x;
}

// ---------------- CSR build (multi-block scan; 1-block scan costs 111us, R18) ----------------

__global__ void k_count(const int* __restrict__ dst, int* __restrict__ indeg, int e_total) {
    int e = blockIdx.x * 256 + threadIdx.x;
    if (e < e_total) atomicAdd(&indeg[dst[e]], 1);
}

__global__ __launch_bounds__(1024) void k_scan_block(const int* __restrict__ in, int* __restrict__ excl,
                                                     int* __restrict__ bsum, int n) {
    __shared__ int sh[1024];
    int t = threadIdx.x;
    int g = blockIdx.x * 1024 + t;
    int v = (g < n) ? in[g] : 0;
    sh[t] = v;
    __syncthreads();
    for (int d = 1; d < 1024; d <<= 1) {
        int x = (t >= d) ? sh[t - d] : 0;
        __syncthreads();
        sh[t] += x;
        __syncthreads();
    }
    if (g < n) excl[g] = sh[t] - v;
    if (t == 1023) bsum[blockIdx.x] = sh[t];
}

__global__ void k_scan_small(int* bsum, int nb) {
    if (threadIdx.x == 0 && blockIdx.x == 0) {
        int run = 0;
        for (int i = 0; i < nb; i++) { int v = bsum[i]; bsum[i] = run; run += v; }
    }
}

__global__ __launch_bounds__(1024) void k_scan_add(int* __restrict__ offs, const int* __restrict__ bsum,
                                                   int* __restrict__ cursor, int n, int e_total) {
    int g = blockIdx.x * 1024 + threadIdx.x;
    if (g < n) {
        int v = offs[g] + bsum[blockIdx.x];
        offs[g] = v;
        cursor[g] = v;
    }
    if (g == 0) offs[n] = e_total;
}

// scatter edges into CSR order; fused: permute edge_attr rows into sea
__global__ void k_scatter_fused(const int* __restrict__ src, const int* __restrict__ dst,
                                const float* __restrict__ edge_attr,
                                int* __restrict__ cursor, int* __restrict__ ssrc,
                                float* __restrict__ sea, int e_total) {
    int e = blockIdx.x * 256 + threadIdx.x;
    if (e < e_total) {
        int d = dst[e];
        int p = atomicAdd(&cursor[d], 1);
        ssrc[p] = src[e];
        const float4* ea = (const float4*)&edge_attr[(size_t)e * 16];
        float4* out = (float4*)&sea[(size_t)p * 16];
        float4 a = ea[0], b = ea[1], c = ea[2], q = ea[3];
        out[0] = a; out[1] = b; out[2] = c; out[3] = q;
    }
}

// fallback scatter (unsorted path)
__global__ void k_scatter(const int* __restrict__ src, const int* __restrict__ dst,
                          int* __restrict__ cursor, int* __restrict__ seid, int* __restrict__ ssrc, int e_total) {
    int e = blockIdx.x * 256 + threadIdx.x;
    if (e < e_total) {
        int d = dst[e];
        int p = atomicAdd(&cursor[d], 1);
        seid[p] = e;
        ssrc[p] = src[e];
    }
}

// ---------------- weight prep: transpose + bf16 ----------------

__global__ void k_prep_w(const float* __restrict__ Wp, const float* __restrict__ Wl,
                         const float* __restrict__ Wr,
                         short* __restrict__ Wpt, short* __restrict__ Wlt, short* __restrict__ Wrt) {
    int i = blockIdx.x * 256 + threadIdx.x;
    if (i < 128 * 64) {
        int nn = i >> 6, k = i & 63;
        Wpt[i] = (short)f2bfu(Wp[k * 128 + nn]);
    }
    if (i < 2 * 128 * 128) {
        int L = i >> 14, r = i & 16383;
        int nn = r >> 7, k = r & 127;
        Wlt[i] = (short)f2bfu(Wl[L * 16384 + k * 128 + nn]);
        Wrt[i] = (short)f2bfu(Wr[L * 16384 + k * 128 + nn]);
    }
}

// ---------------- LN helper ----------------

__device__ __forceinline__ void ln_to_shn_bf16(float a0[4][4], const float* __restrict__ lng,
                                               const float* __restrict__ lnb, short* __restrict__ shn,
                                               int tr, int tc) {
    float4 g4 = *(const float4*)&lng[tc];
    float4 b4 = *(const float4*)&lnb[tc];
#pragma unroll
    for (int j = 0; j < 4; j++) {
        float s = (a0[j][0] + a0[j][1]) + (a0[j][2] + a0[j][3]);
        float ss = a0[j][0] * a0[j][0] + a0[j][1] * a0[j][1] + a0[j][2] * a0[j][2] + a0[j][3] * a0[j][3];
        s = half_sum32(s);
        ss = half_sum32(ss);
        float mu = s * (1.f / 128.f);
        float var = ss * (1.f / 128.f) - mu * mu;
        float rs = rsqrtf(var + 1e-5f);
        float ox = (a0[j][0] - mu) * rs * g4.x + b4.x;
        float oy = (a0[j][1] - mu) * rs * g4.y + b4.y;
        float oz = (a0[j][2] - mu) * rs * g4.z + b4.z;
        float ow = (a0[j][3] - mu) * rs * g4.w + b4.w;
        uint2 pk;
        pk.x = f2bfu(ox) | (f2bfu(oy) << 16);
        pk.y = f2bfu(oz) | (f2bfu(ow) << 16);
        *(uint2*)&shn[(tr + j) * 136 + tc] = pk;
    }
}

// ---------------- per-wave dual-GEMM MFMA body ----------------

__device__ __forceinline__ void dual_gemm_mfma(const short* __restrict__ shn,
                                               const short* __restrict__ Wlt, const float* __restrict__ bl,
                                               const short* __restrict__ Wrt, const float* __restrict__ br,
                                               float* __restrict__ xl, float* __restrict__ xr,
                                               int t, int row0, int n) {
    int w = t >> 6, l = t & 63;
    int lr = l & 15, lg = l >> 4;
    const short* Wt = (w & 2) ? Wrt : Wlt;
    const float* bias = (w & 2) ? br : bl;
    float* out = (w & 2) ? xr : xl;
    int mt = w & 1;

    bf16x8 af[4];
#pragma unroll
    for (int kb = 0; kb < 4; kb++)
        af[kb] = *(const bf16x8*)&shn[(mt * 16 + lr) * 136 + kb * 32 + lg * 8];

#pragma unroll
    for (int n0 = 0; n0 < 8; n0++) {
        float b = bias[n0 * 16 + lr];
        f32x4 acc = {b, b, b, b};
#pragma unroll
        for (int kb = 0; kb < 4; kb++) {
            bf16x8 bf = *(const bf16x8*)&Wt[(size_t)(n0 * 16 + lr) * 128 + kb * 32 + lg * 8];
            acc = __builtin_amdgcn_mfma_f32_16x16x32_bf16(af[kb], bf, acc, 0, 0, 0);
        }
#pragma unroll
        for (int r = 0; r < 4; r++) {
            int row = row0 + mt * 16 + lg * 4 + r;
            if (row < n) out[(size_t)row * 128 + n0 * 16 + lr] = acc[r];
        }
    }
}

// ---------------- layer-0 fused: proj(MFMA) + LN + dual GEMM(MFMA) ----------------

__global__ __launch_bounds__(256, 4) void k_ln_gemm_first(const float* __restrict__ x, const short* __restrict__ Wpt,
                                                          const float* __restrict__ bp,
                                                          const float* __restrict__ lng, const float* __restrict__ lnb,
                                                          const short* __restrict__ Wlt, const float* __restrict__ bl,
                                                          const short* __restrict__ Wrt, const float* __restrict__ br,
                                                          float* __restrict__ h, float* __restrict__ xl,
                                                          float* __restrict__ xr, int n) {
    __shared__ short shx[32 * 72];
    __shared__ float sh_h[32 * 132];
    __shared__ short shn[32 * 136];
    int t = threadIdx.x;
    int row0 = blockIdx.x * 32;
    int nrows = min(32, n - row0);

    for (int c = t; c < 512; c += 256) {
        int r = c >> 4, c4 = (c & 15) * 4;
        float4 v = make_float4(0.f, 0.f, 0.f, 0.f);
        if (r < nrows) v = ((const float4*)x)[(size_t)(row0 + r) * 16 + (c & 15)];
        uint2 pk;
        pk.x = f2bfu(v.x) | (f2bfu(v.y) << 16);
        pk.y = f2bfu(v.z) | (f2bfu(v.w) << 16);
        *(uint2*)&shx[r * 72 + c4] = pk;
    }
    __syncthreads();

    {
        int w = t >> 6, l = t & 63;
        int lr = l & 15, lg = l >> 4;
        int mt = w & 1, n0base = (w >> 1) * 4;
        bf16x8 axf[2];
#pragma unroll
        for (int kb = 0; kb < 2; kb++)
            axf[kb] = *(const bf16x8*)&shx[(mt * 16 + lr) * 72 + kb * 32 + lg * 8];
#pragma unroll
        for (int i = 0; i < 4; i++) {
            int n0 = n0base + i;
            float b = bp[n0 * 16 + lr];
            f32x4 acc = {b, b, b, b};
#pragma unroll
            for (int kb = 0; kb < 2; kb++) {
                bf16x8 bf = *(const bf16x8*)&Wpt[(size_t)(n0 * 16 + lr) * 64 + kb * 32 + lg * 8];
                acc = __builtin_amdgcn_mfma_f32_16x16x32_bf16(axf[kb], bf, acc, 0, 0, 0);
            }
#pragma unroll
            for (int r = 0; r < 4; r++)
                sh_h[(mt * 16 + lg * 4 + r) * 132 + n0 * 16 + lr] = acc[r];
        }
    }
    __syncthreads();

    int tr = (t >> 5) * 4, tc = (t & 31) * 4;
    float a0[4][4];
#pragma unroll
    for (int j = 0; j < 4; j++) {
        float4 v = *(const float4*)&sh_h[(tr + j) * 132 + tc];
        a0[j][0] = v.x; a0[j][1] = v.y; a0[j][2] = v.z; a0[j][3] = v.w;
        int r = row0 + tr + j;
        if (r < n) *(float4*)&h[(size_t)r * 128 + tc] = v;
    }
    ln_to_shn_bf16(a0, lng, lnb, shn, tr, tc);
    __syncthreads();

    dual_gemm_mfma(shn, Wlt, bl, Wrt, br, xl, xr, t, row0, n);
}

// ---------------- layer-1: LN + dual GEMM (MFMA) ----------------

__global__ __launch_bounds__(256, 4) void k_ln_gemm(const float* __restrict__ h,
                                                    const float* __restrict__ lng, const float* __restrict__ lnb,
                                                    const short* __restrict__ Wlt, const float* __restrict__ bl,
                                                    const short* __restrict__ Wrt, const float* __restrict__ br,
                                                    float* __restrict__ xl, float* __restrict__ xr, int n) {
    __shared__ short shn[32 * 136];
    int t = threadIdx.x;
    int row0 = blockIdx.x * 32;
    int tr = (t >> 5) * 4, tc = (t & 31) * 4;

    float a0[4][4];
#pragma unroll
    for (int j = 0; j < 4; j++) {
        int r = row0 + tr + j;
        float4 v = make_float4(0.f, 0.f, 0.f, 0.f);
        if (r < n) v = *(const float4*)&h[(size_t)r * 128 + tc];
        a0[j][0] = v.x; a0[j][1] = v.y; a0[j][2] = v.z; a0[j][3] = v.w;
    }
    ln_to_shn_bf16(a0, lng, lnb, shn, tr, tc);
    __syncthreads();

    dual_gemm_mfma(shn, Wlt, bl, Wrt, br, xl, xr, t, row0, n);
}

// ---------------- GAT aggregate: batch-16 gather staging ----------------
// 1280 blocks (R22: 2048 hurt). All 16 lx gathers issued up front (2x MLP
// depth vs G=8); MAC/reduce/exp in two sub-batches of 8 (v[8]/p[8] reused).
// Invalid tail edges: clamped index + predicated wv=0. Keep lb(256,5)
// budget=102 (64-budgets spill: R7/R8/R10). fp32 operands (R21: bf16 hurt).

#define AGG_BLOCKS 1280

template <bool SORTED>
__global__ __launch_bounds__(256, 5) void k_gat_agg(const float* __restrict__ xl, const float* __restrict__ xr,
                                                    const float* __restrict__ eattr,
                                                    const int* __restrict__ offs,
                                                    const int* __restrict__ seid, const int* __restrict__ ssrc,
                                                    const float* __restrict__ We, const float* __restrict__ att,
                                                    const float* __restrict__ bout,
                                                    const float* __restrict__ hin, float* __restrict__ hout, int n) {
    int wid = threadIdx.x >> 6;
    int lane = threadIdx.x & 63;
    int gwave = blockIdx.x * 4 + wid;
    const int nwaves = AGG_BLOCKS * 4;

    int chb = (lane >> 5) * 64 + (lane & 31) * 2;
    const float* xl_lane = xl + chb;

    v2f we[16];
#pragma unroll
    for (int k = 0; k < 16; k++) we[k] = *(const v2f*)&We[k * 128 + chb];
    v2f av = *(const v2f*)&att[chb];
    v2f bo = *(const v2f*)&bout[chb];

    for (int node = gwave; node < n; node += nwaves) {
        v2f xr2 = *(const v2f*)&xr[node * 128 + chb];
        int s = rfl(offs[node]);
        int e = rfl(offs[node + 1]);
        float den = 0.f;
        v2f A = pksplat(0.f);

        for (int j = s; j < e; j += 16) {
            // stage: all 16 gathers in flight (clamped to node range; tail predicated)
            v2f lx[16];
#pragma unroll
            for (int g = 0; g < 16; g++) {
                int jg = j + g;
                jg = (jg < e) ? jg : (e - 1);
                int sn = rfl(ssrc[jg]);
                lx[g] = *(const v2f*)(xl_lane + sn * 128);
            }
#pragma unroll
            for (int half = 0; half < 2; half++) {
                const float* ep[8];
#pragma unroll
                for (int g = 0; g < 8; g++) {
                    int jg = j + half * 8 + g;
                    jg = (jg < e) ? jg : (e - 1);
                    int r = SORTED ? jg : rfl(seid[jg]);
                    ep[g] = &eattr[(size_t)r * 16];
                }
                v2f v[8];
#pragma unroll
                for (int g = 0; g < 8; g++) v[g] = lx[half * 8 + g] + xr2;
#pragma unroll
                for (int k = 0; k < 16; k++) {
#pragma unroll
                    for (int g = 0; g < 8; g++) v[g] = pkfma(pksplat(ep[g][k]), we[k], v[g]);
                }
                float p[8];
#pragma unroll
                for (int g = 0; g < 8; g++) {
                    v2f tt = pklrelu(v[g]) * av;
                    p[g] = tt.x + tt.y;
                }
#pragma unroll
                for (int g = 0; g < 8; g++) p[g] = half_sum32(p[g]);
#pragma unroll
                for (int g = 0; g < 8; g++) {
                    float wv = (j + half * 8 + g < e) ? __expf(p[g]) : 0.f;
                    den += wv;
                    A = pkfma(pksplat(wv), lx[half * 8 + g], A);
                }
            }
        }

        float inv = (e > s) ? (1.f / den) : 0.f;
        v2f hg = pkfma(A, pksplat(inv), bo);
        hg = __builtin_elementwise_max(hg, pksplat(0.f));
        v2f hv = *(const v2f*)&hin[node * 128 + chb];
        *(v2f*)&hout[node * 128 + chb] = hv + hg;
    }
}

// ---------------- classifier ----------------

__global__ __launch_bounds__(256) void k_cls_lite(const float* __restrict__ emb, const float* __restrict__ Wc,
                                                  const float* __restrict__ bc, float* __restrict__ out_cls, int n) {
    int wid = threadIdx.x >> 6;
    int lane = threadIdx.x & 63;
    int node = blockIdx.x * 4 + wid;
    if (node >= n) return;
    float h0 = emb[(size_t)node * 128 + lane];
    float h1 = emb[(size_t)node * 128 + 64 + lane];
    float p[10];
#pragma unroll
    for (int k = 0; k < 10; k++) p[k] = h0 * Wc[lane * 10 + k] + h1 * Wc[(64 + lane) * 10 + k];
#pragma unroll
    for (int o = 32; o; o >>= 1) {
#pragma unroll
        for (int k = 0; k < 10; k++) p[k] += __shfl_xor(p[k], o, 64);
    }
    if (lane == 0) {
#pragma unroll
        for (int k = 0; k < 10; k++) out_cls[(size_t)node * 10 + k] = p[k] + bc[k];
    }
}

extern "C" void kernel_launch(void* const* d_in, const int* in_sizes, int n_in,
                              void* d_out, int out_size, void* d_ws, size_t ws_size,
                              hipStream_t stream) {
    const float* x         = (const float*)d_in[0];
    const int*   edge_idx  = (const int*)d_in[1];
    const float* edge_attr = (const float*)d_in[2];
    const float* Wp        = (const float*)d_in[3];
    const float* bp        = (const float*)d_in[4];
    const float* lng       = (const float*)d_in[5];
    const float* lnb       = (const float*)d_in[6];
    const float* Wl        = (const float*)d_in[7];
    const float* bl        = (const float*)d_in[8];
    const float* Wr        = (const float*)d_in[9];
    const float* br        = (const float*)d_in[10];
    const float* We        = (const float*)d_in[11];
    const float* att       = (const float*)d_in[12];
    const float* bout      = (const float*)d_in[13];
    const float* Wc        = (const float*)d_in[14];
    const float* bc        = (const float*)d_in[15];

    const int N = N_NODES, E = N_EDGES;

    char* w = (char*)d_ws;
    size_t used = 0;
    auto take = [&](size_t bytes) -> void* {
        void* p = (void*)(w + used);
        used += (bytes + 255) & ~(size_t)255;
        return p;
    };
    float* h      = (float*)take((size_t)N * 128 * 4);
    float* xl     = (float*)take((size_t)N * 128 * 4);
    float* xr     = (float*)take((size_t)N * 128 * 4);
    int*   indeg  = (int*)take((size_t)N * 4);
    int*   offs   = (int*)take((size_t)(N + 1) * 4);
    int*   cursor = (int*)take((size_t)N * 4);
    int*   bsum   = (int*)take(64 * 4);
    int*   seid   = (int*)take((size_t)E * 4);
    int*   ssrc   = (int*)take((size_t)E * 4);
    short* Wpt    = (short*)take((size_t)128 * 64 * 2);
    short* Wlt    = (short*)take((size_t)2 * 128 * 128 * 2);
    short* Wrt    = (short*)take((size_t)2 * 128 * 128 * 2);
    float* sea    = (float*)take((size_t)E * 16 * 4);
    bool sorted_ok = (used <= ws_size);

    float* out_cls = (float*)d_out;
    float* out_emb = (float*)d_out + (size_t)N * KCLS;

    const int* srcArr = edge_idx;
    const int* dstArr = edge_idx + E;

    (void)hipMemsetAsync(indeg, 0, (size_t)N * 4, stream);
    k_count<<<(E + 255) / 256, 256, 0, stream>>>(dstArr, indeg, E);
    int NB = (N + 1023) / 1024;
    k_scan_block<<<NB, 1024, 0, stream>>>(indeg, offs, bsum, N);
    k_scan_small<<<1, 64, 0, stream>>>(bsum, NB);
    k_scan_add<<<NB, 1024, 0, stream>>>(offs, bsum, cursor, N, E);
    if (sorted_ok)
        k_scatter_fused<<<(E + 255) / 256, 256, 0, stream>>>(srcArr, dstArr, edge_attr, cursor, ssrc, sea, E);
    else
        k_scatter<<<(E + 255) / 256, 256, 0, stream>>>(srcArr, dstArr, cursor, seid, ssrc, E);

    k_prep_w<<<128, 256, 0, stream>>>(Wp, Wl, Wr, Wpt, Wlt, Wrt);

    k_ln_gemm_first<<<(N + 31) / 32, 256, 0, stream>>>(
        x, Wpt, bp, lng, lnb,
        Wlt, bl, Wrt, br, h, xl, xr, N);
    if (sorted_ok)
        k_gat_agg<true><<<AGG_BLOCKS, 256, 0, stream>>>(
            xl, xr, sea, offs, seid, ssrc, We, att, bout, h, h, N);
    else
        k_gat_agg<false><<<AGG_BLOCKS, 256, 0, stream>>>(
            xl, xr, edge_attr, offs, seid, ssrc, We, att, bout, h, h, N);

    k_ln_gemm<<<(N + 31) / 32, 256, 0, stream>>>(
        h, lng + 128, lnb + 128,
        Wlt + 16384, bl + 128,
        Wrt + 16384, br + 128,
        xl, xr, N);
    if (sorted_ok)
        k_gat_agg<true><<<AGG_BLOCKS, 256, 0, stream>>>(
            xl, xr, sea, offs, seid, ssrc,
            We + 16 * 128, att + 128, bout + 128, h, out_emb, N);
    else
        k_gat_agg<false><<<AGG_BLOCKS, 256, 0, stream>>>(
            xl, xr, edge_attr, offs, seid, ssrc,
            We + 16 * 128, att + 128, bout + 128, h, out_emb, N);

    k_cls_lite<<<(N + 3) / 4, 256, 0, stream>>>(out_emb, Wc, bc, out_cls, N);
}

// Round 24
// 388.457 us; speedup vs baseline: 1.2569x; 1.2569x over previous
//
#include <hip/hip_runtime.h>
#include <math.h>

#define N_NODES 50000
#define N_EDGES 800000
#define FDIM 128
#define KCLS 10

typedef float v2f __attribute__((ext_vector_type(2)));
typedef short bf16x8 __attribute__((ext_vector_type(8)));
typedef float f32x4 __attribute__((ext_vector_type(4)));

__device__ __forceinline__ v2f pksplat(float a) { v2f r; r.x = a; r.y = a; return r; }
__device__ __forceinline__ v2f pkfma(v2f a, v2f b, v2f c) { return __builtin_elementwise_fma(a, b, c); }
__device__ __forceinline__ v2f pklrelu(v2f v) {
    v2f z = pksplat(0.f);
    v2f mx = __builtin_elementwise_max(v, z);
    v2f mn = __builtin_elementwise_min(v, z);
    return pkfma(pksplat(0.2f), mn, mx);
}
__device__ __forceinline__ int rfl(int v) { return __builtin_amdgcn_readfirstlane(v); }

// fp32 -> bf16 bits, round-to-nearest-even
__device__ __forceinline__ unsigned int f2bfu(float f) {
    unsigned int u = __float_as_uint(f);
    u += 0x7FFFu + ((u >> 16) & 1u);
    return u >> 16;
}

// sum over each 32-lane half, all lanes receive the result.
__device__ __forceinline__ float half_sum32(float x) {
    int v;
    v = __builtin_amdgcn_update_dpp(0, __float_as_int(x), 0xB1, 0xF, 0xF, true);   // quad_perm(1,0,3,2)
    x += __int_as_float(v);
    v = __builtin_amdgcn_update_dpp(0, __float_as_int(x), 0x4E, 0xF, 0xF, true);   // quad_perm(2,3,0,1)
    x += __int_as_float(v);
    v = __builtin_amdgcn_update_dpp(0, __float_as_int(x), 0x124, 0xF, 0xF, true);  // row_ror:4
    x += __int_as_float(v);
    v = __builtin_amdgcn_update_dpp(0, __float_as_int(x), 0x128, 0xF, 0xF, true);  // row_ror:8
    x += __int_as_float(v);
    v = __builtin_amdgcn_ds_swizzle(__float_as_int(x), 0x401F);                    // xor16
    x += __int_as_float(v);
    return x;
}

// ---------------- CSR build (multi-block scan; 1-block scan costs 111us, R18) ----------------

__global__ void k_count(const int* __restrict__ dst, int* __restrict__ indeg, int e_total) {
    int e = blockIdx.x * 256 + threadIdx.x;
    if (e < e_total) atomicAdd(&indeg[dst[e]], 1);
}

__global__ __launch_bounds__(1024) void k_scan_block(const int* __restrict__ in, int* __restrict__ excl,
                                                     int* __restrict__ bsum, int n) {
    __shared__ int sh[1024];
    int t = threadIdx.x;
    int g = blockIdx.x * 1024 + t;
    int v = (g < n) ? in[g] : 0;
    sh[t] = v;
    __syncthreads();
    for (int d = 1; d < 1024; d <<= 1) {
        int x = (t >= d) ? sh[t - d] : 0;
        __syncthreads();
        sh[t] += x;
        __syncthreads();
    }
    if (g < n) excl[g] = sh[t] - v;
    if (t == 1023) bsum[blockIdx.x] = sh[t];
}

__global__ void k_scan_small(int* bsum, int nb) {
    if (threadIdx.x == 0 && blockIdx.x == 0) {
        int run = 0;
        for (int i = 0; i < nb; i++) { int v = bsum[i]; bsum[i] = run; run += v; }
    }
}

__global__ __launch_bounds__(1024) void k_scan_add(int* __restrict__ offs, const int* __restrict__ bsum,
                                                   int* __restrict__ cursor, int n, int e_total) {
    int g = blockIdx.x * 1024 + threadIdx.x;
    if (g < n) {
        int v = offs[g] + bsum[blockIdx.x];
        offs[g] = v;
        cursor[g] = v;
    }
    if (g == 0) offs[n] = e_total;
}

// scatter edges into CSR order; fused: permute edge_attr rows into sea
__global__ void k_scatter_fused(const int* __restrict__ src, const int* __restrict__ dst,
                                const float* __restrict__ edge_attr,
                                int* __restrict__ cursor, int* __restrict__ ssrc,
                                float* __restrict__ sea, int e_total) {
    int e = blockIdx.x * 256 + threadIdx.x;
    if (e < e_total) {
        int d = dst[e];
        int p = atomicAdd(&cursor[d], 1);
        ssrc[p] = src[e];
        const float4* ea = (const float4*)&edge_attr[(size_t)e * 16];
        float4* out = (float4*)&sea[(size_t)p * 16];
        float4 a = ea[0], b = ea[1], c = ea[2], q = ea[3];
        out[0] = a; out[1] = b; out[2] = c; out[3] = q;
    }
}

// fallback scatter (unsorted path)
__global__ void k_scatter(const int* __restrict__ src, const int* __restrict__ dst,
                          int* __restrict__ cursor, int* __restrict__ seid, int* __restrict__ ssrc, int e_total) {
    int e = blockIdx.x * 256 + threadIdx.x;
    if (e < e_total) {
        int d = dst[e];
        int p = atomicAdd(&cursor[d], 1);
        seid[p] = e;
        ssrc[p] = src[e];
    }
}

// ---------------- weight prep: transpose + bf16 ----------------

__global__ void k_prep_w(const float* __restrict__ Wp, const float* __restrict__ Wl,
                         const float* __restrict__ Wr,
                         short* __restrict__ Wpt, short* __restrict__ Wlt, short* __restrict__ Wrt) {
    int i = blockIdx.x * 256 + threadIdx.x;
    if (i < 128 * 64) {
        int nn = i >> 6, k = i & 63;
        Wpt[i] = (short)f2bfu(Wp[k * 128 + nn]);
    }
    if (i < 2 * 128 * 128) {
        int L = i >> 14, r = i & 16383;
        int nn = r >> 7, k = r & 127;
        Wlt[i] = (short)f2bfu(Wl[L * 16384 + k * 128 + nn]);
        Wrt[i] = (short)f2bfu(Wr[L * 16384 + k * 128 + nn]);
    }
}

// ---------------- LN helper ----------------

__device__ __forceinline__ void ln_to_shn_bf16(float a0[4][4], const float* __restrict__ lng,
                                               const float* __restrict__ lnb, short* __restrict__ shn,
                                               int tr, int tc) {
    float4 g4 = *(const float4*)&lng[tc];
    float4 b4 = *(const float4*)&lnb[tc];
#pragma unroll
    for (int j = 0; j < 4; j++) {
        float s = (a0[j][0] + a0[j][1]) + (a0[j][2] + a0[j][3]);
        float ss = a0[j][0] * a0[j][0] + a0[j][1] * a0[j][1] + a0[j][2] * a0[j][2] + a0[j][3] * a0[j][3];
        s = half_sum32(s);
        ss = half_sum32(ss);
        float mu = s * (1.f / 128.f);
        float var = ss * (1.f / 128.f) - mu * mu;
        float rs = rsqrtf(var + 1e-5f);
        float ox = (a0[j][0] - mu) * rs * g4.x + b4.x;
        float oy = (a0[j][1] - mu) * rs * g4.y + b4.y;
        float oz = (a0[j][2] - mu) * rs * g4.z + b4.z;
        float ow = (a0[j][3] - mu) * rs * g4.w + b4.w;
        uint2 pk;
        pk.x = f2bfu(ox) | (f2bfu(oy) << 16);
        pk.y = f2bfu(oz) | (f2bfu(ow) << 16);
        *(uint2*)&shn[(tr + j) * 136 + tc] = pk;
    }
}

// ---------------- per-wave dual-GEMM MFMA body ----------------

__device__ __forceinline__ void dual_gemm_mfma(const short* __restrict__ shn,
                                               const short* __restrict__ Wlt, const float* __restrict__ bl,
                                               const short* __restrict__ Wrt, const float* __restrict__ br,
                                               float* __restrict__ xl, float* __restrict__ xr,
                                               int t, int row0, int n) {
    int w = t >> 6, l = t & 63;
    int lr = l & 15, lg = l >> 4;
    const short* Wt = (w & 2) ? Wrt : Wlt;
    const float* bias = (w & 2) ? br : bl;
    float* out = (w & 2) ? xr : xl;
    int mt = w & 1;

    bf16x8 af[4];
#pragma unroll
    for (int kb = 0; kb < 4; kb++)
        af[kb] = *(const bf16x8*)&shn[(mt * 16 + lr) * 136 + kb * 32 + lg * 8];

#pragma unroll
    for (int n0 = 0; n0 < 8; n0++) {
        float b = bias[n0 * 16 + lr];
        f32x4 acc = {b, b, b, b};
#pragma unroll
        for (int kb = 0; kb < 4; kb++) {
            bf16x8 bf = *(const bf16x8*)&Wt[(size_t)(n0 * 16 + lr) * 128 + kb * 32 + lg * 8];
            acc = __builtin_amdgcn_mfma_f32_16x16x32_bf16(af[kb], bf, acc, 0, 0, 0);
        }
#pragma unroll
        for (int r = 0; r < 4; r++) {
            int row = row0 + mt * 16 + lg * 4 + r;
            if (row < n) out[(size_t)row * 128 + n0 * 16 + lr] = acc[r];
        }
    }
}

// ---------------- layer-0 fused: proj(MFMA) + LN + dual GEMM(MFMA) ----------------

__global__ __launch_bounds__(256, 4) void k_ln_gemm_first(const float* __restrict__ x, const short* __restrict__ Wpt,
                                                          const float* __restrict__ bp,
                                                          const float* __restrict__ lng, const float* __restrict__ lnb,
                                                          const short* __restrict__ Wlt, const float* __restrict__ bl,
                                                          const short* __restrict__ Wrt, const float* __restrict__ br,
                                                          float* __restrict__ h, float* __restrict__ xl,
                                                          float* __restrict__ xr, int n) {
    __shared__ short shx[32 * 72];
    __shared__ float sh_h[32 * 132];
    __shared__ short shn[32 * 136];
    int t = threadIdx.x;
    int row0 = blockIdx.x * 32;
    int nrows = min(32, n - row0);

    for (int c = t; c < 512; c += 256) {
        int r = c >> 4, c4 = (c & 15) * 4;
        float4 v = make_float4(0.f, 0.f, 0.f, 0.f);
        if (r < nrows) v = ((const float4*)x)[(size_t)(row0 + r) * 16 + (c & 15)];
        uint2 pk;
        pk.x = f2bfu(v.x) | (f2bfu(v.y) << 16);
        pk.y = f2bfu(v.z) | (f2bfu(v.w) << 16);
        *(uint2*)&shx[r * 72 + c4] = pk;
    }
    __syncthreads();

    {
        int w = t >> 6, l = t & 63;
        int lr = l & 15, lg = l >> 4;
        int mt = w & 1, n0base = (w >> 1) * 4;
        bf16x8 axf[2];
#pragma unroll
        for (int kb = 0; kb < 2; kb++)
            axf[kb] = *(const bf16x8*)&shx[(mt * 16 + lr) * 72 + kb * 32 + lg * 8];
#pragma unroll
        for (int i = 0; i < 4; i++) {
            int n0 = n0base + i;
            float b = bp[n0 * 16 + lr];
            f32x4 acc = {b, b, b, b};
#pragma unroll
            for (int kb = 0; kb < 2; kb++) {
                bf16x8 bf = *(const bf16x8*)&Wpt[(size_t)(n0 * 16 + lr) * 64 + kb * 32 + lg * 8];
                acc = __builtin_amdgcn_mfma_f32_16x16x32_bf16(axf[kb], bf, acc, 0, 0, 0);
            }
#pragma unroll
            for (int r = 0; r < 4; r++)
                sh_h[(mt * 16 + lg * 4 + r) * 132 + n0 * 16 + lr] = acc[r];
        }
    }
    __syncthreads();

    int tr = (t >> 5) * 4, tc = (t & 31) * 4;
    float a0[4][4];
#pragma unroll
    for (int j = 0; j < 4; j++) {
        float4 v = *(const float4*)&sh_h[(tr + j) * 132 + tc];
        a0[j][0] = v.x; a0[j][1] = v.y; a0[j][2] = v.z; a0[j][3] = v.w;
        int r = row0 + tr + j;
        if (r < n) *(float4*)&h[(size_t)r * 128 + tc] = v;
    }
    ln_to_shn_bf16(a0, lng, lnb, shn, tr, tc);
    __syncthreads();

    dual_gemm_mfma(shn, Wlt, bl, Wrt, br, xl, xr, t, row0, n);
}

// ---------------- layer-1: LN + dual GEMM (MFMA) ----------------

__global__ __launch_bounds__(256, 4) void k_ln_gemm(const float* __restrict__ h,
                                                    const float* __restrict__ lng, const float* __restrict__ lnb,
                                                    const short* __restrict__ Wlt, const float* __restrict__ bl,
                                                    const short* __restrict__ Wrt, const float* __restrict__ br,
                                                    float* __restrict__ xl, float* __restrict__ xr, int n) {
    __shared__ short shn[32 * 136];
    int t = threadIdx.x;
    int row0 = blockIdx.x * 32;
    int tr = (t >> 5) * 4, tc = (t & 31) * 4;

    float a0[4][4];
#pragma unroll
    for (int j = 0; j < 4; j++) {
        int r = row0 + tr + j;
        float4 v = make_float4(0.f, 0.f, 0.f, 0.f);
        if (r < n) v = *(const float4*)&h[(size_t)r * 128 + tc];
        a0[j][0] = v.x; a0[j][1] = v.y; a0[j][2] = v.z; a0[j][3] = v.w;
    }
    ln_to_shn_bf16(a0, lng, lnb, shn, tr, tc);
    __syncthreads();

    dual_gemm_mfma(shn, Wlt, bl, Wrt, br, xl, xr, t, row0, n);
}

// ---------------- GAT aggregate (R19-exact: lb(256,5), 1280 blocks, G=8/4/1, DPP) ----------------
// Session-tested floor: G-unroll x2, residency up/down, DPP, exp2, bf16
// operands, dual-node, batch-16 all fail to beat this (103us/dispatch).
// Keep lb budget 102 (64-budgets spill: R7/R8/R10); 1280 blocks (2048 hurt:
// R22); fp32 operands (bf16 hurt: R21); sorted sea (seid-indirect hurt: R17).

#define AGG_BLOCKS 1280

template <bool SORTED, int G>
__device__ __forceinline__ void grpN(const float* __restrict__ xl_lane, const float* __restrict__ eattr,
                                     const int* __restrict__ seid, const int* __restrict__ ssrc,
                                     int j, v2f xr2, const v2f* we, v2f av,
                                     float& den, v2f& A) {
    v2f lx[G];
    const float* ep[G];
#pragma unroll
    for (int g = 0; g < G; g++) {
        int sn = rfl(ssrc[j + g]);
        lx[g] = *(const v2f*)(xl_lane + sn * 128);
        int r = SORTED ? (j + g) : rfl(seid[j + g]);
        ep[g] = &eattr[(size_t)r * 16];
    }
    v2f v[G];
#pragma unroll
    for (int g = 0; g < G; g++) v[g] = lx[g] + xr2;
#pragma unroll
    for (int k = 0; k < 16; k++) {
#pragma unroll
        for (int g = 0; g < G; g++) v[g] = pkfma(pksplat(ep[g][k]), we[k], v[g]);
    }
    float p[G];
#pragma unroll
    for (int g = 0; g < G; g++) {
        v2f t = pklrelu(v[g]) * av;
        p[g] = t.x + t.y;
    }
#pragma unroll
    for (int g = 0; g < G; g++) p[g] = half_sum32(p[g]);
#pragma unroll
    for (int g = 0; g < G; g++) {
        float wv = __expf(p[g]);
        den += wv;
        A = pkfma(pksplat(wv), lx[g], A);
    }
}

template <bool SORTED>
__global__ __launch_bounds__(256, 5) void k_gat_agg(const float* __restrict__ xl, const float* __restrict__ xr,
                                                    const float* __restrict__ eattr,
                                                    const int* __restrict__ offs,
                                                    const int* __restrict__ seid, const int* __restrict__ ssrc,
                                                    const float* __restrict__ We, const float* __restrict__ att,
                                                    const float* __restrict__ bout,
                                                    const float* __restrict__ hin, float* __restrict__ hout, int n) {
    int wid = threadIdx.x >> 6;
    int lane = threadIdx.x & 63;
    int gwave = blockIdx.x * 4 + wid;
    const int nwaves = AGG_BLOCKS * 4;

    int chb = (lane >> 5) * 64 + (lane & 31) * 2;
    const float* xl_lane = xl + chb;

    v2f we[16];
#pragma unroll
    for (int k = 0; k < 16; k++) we[k] = *(const v2f*)&We[k * 128 + chb];
    v2f av = *(const v2f*)&att[chb];
    v2f bo = *(const v2f*)&bout[chb];

    for (int node = gwave; node < n; node += nwaves) {
        v2f xr2 = *(const v2f*)&xr[node * 128 + chb];
        int s = rfl(offs[node]);
        int e = rfl(offs[node + 1]);
        float den = 0.f;
        v2f A = pksplat(0.f);

        int j = s;
        for (; j + 8 <= e; j += 8)
            grpN<SORTED, 8>(xl_lane, eattr, seid, ssrc, j, xr2, we, av, den, A);
        if (j + 4 <= e) {
            grpN<SORTED, 4>(xl_lane, eattr, seid, ssrc, j, xr2, we, av, den, A);
            j += 4;
        }
        for (; j < e; j++)
            grpN<SORTED, 1>(xl_lane, eattr, seid, ssrc, j, xr2, we, av, den, A);

        float inv = (e > s) ? (1.f / den) : 0.f;
        v2f hg = pkfma(A, pksplat(inv), bo);
        hg = __builtin_elementwise_max(hg, pksplat(0.f));
        v2f hv = *(const v2f*)&hin[node * 128 + chb];
        *(v2f*)&hout[node * 128 + chb] = hv + hg;
    }
}

// ---------------- classifier ----------------

__global__ __launch_bounds__(256) void k_cls_lite(const float* __restrict__ emb, const float* __restrict__ Wc,
                                                  const float* __restrict__ bc, float* __restrict__ out_cls, int n) {
    int wid = threadIdx.x >> 6;
    int lane = threadIdx.x & 63;
    int node = blockIdx.x * 4 + wid;
    if (node >= n) return;
    float h0 = emb[(size_t)node * 128 + lane];
    float h1 = emb[(size_t)node * 128 + 64 + lane];
    float p[10];
#pragma unroll
    for (int k = 0; k < 10; k++) p[k] = h0 * Wc[lane * 10 + k] + h1 * Wc[(64 + lane) * 10 + k];
#pragma unroll
    for (int o = 32; o; o >>= 1) {
#pragma unroll
        for (int k = 0; k < 10; k++) p[k] += __shfl_xor(p[k], o, 64);
    }
    if (lane == 0) {
#pragma unroll
        for (int k = 0; k < 10; k++) out_cls[(size_t)node * 10 + k] = p[k] + bc[k];
    }
}

extern "C" void kernel_launch(void* const* d_in, const int* in_sizes, int n_in,
                              void* d_out, int out_size, void* d_ws, size_t ws_size,
                              hipStream_t stream) {
    const float* x         = (const float*)d_in[0];
    const int*   edge_idx  = (const int*)d_in[1];
    const float* edge_attr = (const float*)d_in[2];
    const float* Wp        = (const float*)d_in[3];
    const float* bp        = (const float*)d_in[4];
    const float* lng       = (const float*)d_in[5];
    const float* lnb       = (const float*)d_in[6];
    const float* Wl        = (const float*)d_in[7];
    const float* bl        = (const float*)d_in[8];
    const float* Wr        = (const float*)d_in[9];
    const float* br        = (const float*)d_in[10];
    const float* We        = (const float*)d_in[11];
    const float* att       = (const float*)d_in[12];
    const float* bout      = (const float*)d_in[13];
    const float* Wc        = (const float*)d_in[14];
    const float* bc        = (const float*)d_in[15];

    const int N = N_NODES, E = N_EDGES;

    char* w = (char*)d_ws;
    size_t used = 0;
    auto take = [&](size_t bytes) -> void* {
        void* p = (void*)(w + used);
        used += (bytes + 255) & ~(size_t)255;
        return p;
    };
    float* h      = (float*)take((size_t)N * 128 * 4);
    float* xl     = (float*)take((size_t)N * 128 * 4);
    float* xr     = (float*)take((size_t)N * 128 * 4);
    int*   indeg  = (int*)take((size_t)N * 4);
    int*   offs   = (int*)take((size_t)(N + 1) * 4);
    int*   cursor = (int*)take((size_t)N * 4);
    int*   bsum   = (int*)take(64 * 4);
    int*   seid   = (int*)take((size_t)E * 4);
    int*   ssrc   = (int*)take((size_t)E * 4);
    short* Wpt    = (short*)take((size_t)128 * 64 * 2);
    short* Wlt    = (short*)take((size_t)2 * 128 * 128 * 2);
    short* Wrt    = (short*)take((size_t)2 * 128 * 128 * 2);
    float* sea    = (float*)take((size_t)E * 16 * 4);
    bool sorted_ok = (used <= ws_size);

    float* out_cls = (float*)d_out;
    float* out_emb = (float*)d_out + (size_t)N * KCLS;

    const int* srcArr = edge_idx;
    const int* dstArr = edge_idx + E;

    (void)hipMemsetAsync(indeg, 0, (size_t)N * 4, stream);
    k_count<<<(E + 255) / 256, 256, 0, stream>>>(dstArr, indeg, E);
    int NB = (N + 1023) / 1024;
    k_scan_block<<<NB, 1024, 0, stream>>>(indeg, offs, bsum, N);
    k_scan_small<<<1, 64, 0, stream>>>(bsum, NB);
    k_scan_add<<<NB, 1024, 0, stream>>>(offs, bsum, cursor, N, E);
    if (sorted_ok)
        k_scatter_fused<<<(E + 255) / 256, 256, 0, stream>>>(srcArr, dstArr, edge_attr, cursor, ssrc, sea, E);
    else
        k_scatter<<<(E + 255) / 256, 256, 0, stream>>>(srcArr, dstArr, cursor, seid, ssrc, E);

    k_prep_w<<<128, 256, 0, stream>>>(Wp, Wl, Wr, Wpt, Wlt, Wrt);

    k_ln_gemm_first<<<(N + 31) / 32, 256, 0, stream>>>(
        x, Wpt, bp, lng, lnb,
        Wlt, bl, Wrt, br, h, xl, xr, N);
    if (sorted_ok)
        k_gat_agg<true><<<AGG_BLOCKS, 256, 0, stream>>>(
            xl, xr, sea, offs, seid, ssrc, We, att, bout, h, h, N);
    else
        k_gat_agg<false><<<AGG_BLOCKS, 256, 0, stream>>>(
            xl, xr, edge_attr, offs, seid, ssrc, We, att, bout, h, h, N);

    k_ln_gemm<<<(N + 31) / 32, 256, 0, stream>>>(
        h, lng + 128, lnb + 128,
        Wlt + 16384, bl + 128,
        Wrt + 16384, br + 128,
        xl, xr, N);
    if (sorted_ok)
        k_gat_agg<true><<<AGG_BLOCKS, 256, 0, stream>>>(
            xl, xr, sea, offs, seid, ssrc,
            We + 16 * 128, att + 128, bout + 128, h, out_emb, N);
    else
        k_gat_agg<false><<<AGG_BLOCKS, 256, 0, stream>>>(
            xl, xr, edge_attr, offs, seid, ssrc,
            We + 16 * 128, att + 128, bout + 128, h, out_emb, N);

    k_cls_lite<<<(N + 3) / 4, 256, 0, stream>>>(out_emb, Wc, bc, out_cls, N);
}